// Round 3
// baseline (326.226 us; speedup 1.0000x reference)
//
#include <hip/hip_runtime.h>

typedef unsigned int u32;
typedef __bf16 bf16_t;
typedef bf16_t bf16x8 __attribute__((ext_vector_type(8)));
typedef float f32x4 __attribute__((ext_vector_type(4)));

#define NB 64
#define GH 56
#define CC 96
#define NH 3
#define MM 7
#define WT 49
#define C3 288
#define LL 3136

// ws layout (bytes): weight fragments only
static constexpr size_t WQ_OFF = 0;                 // 54 frags * 1024 B
static constexpr size_t WP_OFF = WQ_OFF + 54 * 1024; // 18 frags * 1024 B
static constexpr size_t BR_OFF = WP_OFF + 18 * 1024; // 288 floats

static __device__ __forceinline__ unsigned short f2bu(float f) {
    union { bf16_t b; unsigned short u; } c; c.b = (bf16_t)f; return c.u;
}
static __device__ __forceinline__ u32 pack2(float a, float b) {
    return (u32)f2bu(a) | ((u32)f2bu(b) << 16);
}
static __device__ __forceinline__ f32x4 mfma16(bf16x8 a, bf16x8 b, f32x4 c) {
    return __builtin_amdgcn_mfma_f32_16x16x32_bf16(a, b, c, 0, 0, 0);
}

// ---------------------------------------------------------------------------
// prep: w_qkv / w_proj -> bf16 B-fragment layout; b_qkv de-interleave.
// B-frag (nt, ks): lane l, elem j = B[32*ks + 8*(l>>4) + j][16*nt + (l&15)]
// qkv col' = which*32 + e  <->  w_qkv col = h*96 + e*3 + which
// ---------------------------------------------------------------------------
__global__ __launch_bounds__(64) void prep_kernel(
    const float* __restrict__ w_qkv, const float* __restrict__ b_qkv,
    const float* __restrict__ w_proj, char* __restrict__ ws)
{
    const int l = threadIdx.x;
    const int blk = blockIdx.x;
    if (blk < 54) {
        const int h = blk / 18, nt = (blk % 18) / 3, ks = blk % 3;
        const int colp = nt * 16 + (l & 15);
        const int e = colp & 31, wh = colp >> 5;
        const int k0 = ks * 32 + (l >> 4) * 8;
        u32 p[4];
        #pragma unroll
        for (int jj = 0; jj < 4; ++jj)
            p[jj] = pack2(w_qkv[(size_t)(k0 + 2*jj    ) * C3 + h * CC + e * 3 + wh],
                          w_qkv[(size_t)(k0 + 2*jj + 1) * C3 + h * CC + e * 3 + wh]);
        uint4 v; v.x = p[0]; v.y = p[1]; v.z = p[2]; v.w = p[3];
        *(uint4*)(ws + WQ_OFF + ((size_t)blk * 64 + l) * 16) = v;
    } else if (blk < 72) {
        const int idx = blk - 54, nt = idx / 3, ks = idx % 3;
        const int n = nt * 16 + (l & 15);
        const int k0 = ks * 32 + (l >> 4) * 8;
        u32 p[4];
        #pragma unroll
        for (int jj = 0; jj < 4; ++jj)
            p[jj] = pack2(w_proj[(size_t)(k0 + 2*jj    ) * CC + n],
                          w_proj[(size_t)(k0 + 2*jj + 1) * CC + n]);
        uint4 v; v.x = p[0]; v.y = p[1]; v.z = p[2]; v.w = p[3];
        *(uint4*)(ws + WP_OFF + ((size_t)idx * 64 + l) * 16) = v;
    } else {
        float* br = (float*)(ws + BR_OFF);
        for (int i = l; i < C3; i += 64) {
            int h = i / CC, c = i % CC;
            br[i] = b_qkv[h * CC + (c & 31) * 3 + (c >> 5)];
        }
    }
}

// ---------------------------------------------------------------------------
// fused: qkv GEMM + window attention + proj, one block per (batch, window).
// 8 waves; wave w owns m-tile (w&3), "half" hi = w>>2.
// ---------------------------------------------------------------------------
__global__ __launch_bounds__(512, 6) void attn_fused_kernel(
    const float* __restrict__ x, const float* __restrict__ rel_bias,
    const char* __restrict__ wsro, const float* __restrict__ b_proj,
    float* __restrict__ out)
{
    __shared__ bf16_t s_x [64][104];  // 13312 B, stride 208 = 13*16B
    __shared__ bf16_t s_q [64][40];   //  5120 B, stride  80 =  5*16B
    __shared__ bf16_t s_k [64][40];   //  5120 B
    __shared__ bf16_t s_vT[32][72];   //  4608 B, stride 144 =  9*16B
    __shared__ bf16_t s_p [64][72];   //  9216 B
    __shared__ bf16_t s_o [64][40];   //  5120 B (per-head O, K=32 proj slab)
    __shared__ float  s_bias[WT][50]; //  9800 B
    // total 52,296 B -> 3 blocks/CU; 24 waves/CU

    const int tid = threadIdx.x;
    const int l = tid & 63, w = tid >> 6;
    const int ln = l & 15, quad = l >> 4;
    const int b = blockIdx.x >> 6, win = blockIdx.x & 63;
    const int wy = win >> 3, wx = win & 7;
    const int m  = w & 3;      // 16-row m-tile of this wave
    const int hi = w >> 2;     // 0/1: which half of the nt space
    const int q0m = 16 * m + quad * 4;

    // ---- stage x window fp32->bf16 (rows >= 49 zeroed), rel_bias ----
    for (int i = tid; i < 1536; i += 512) {
        const int t = i / 24, c4 = (i % 24) * 4;
        float4 xv = {0.f, 0.f, 0.f, 0.f};
        if (t < WT) {
            const int grow = (wy * MM + t / MM) * GH + wx * MM + t % MM;
            xv = *(const float4*)&x[((size_t)b * LL + grow) * CC + c4];
        }
        ushort4 pv;
        pv.x = f2bu(xv.x); pv.y = f2bu(xv.y); pv.z = f2bu(xv.z); pv.w = f2bu(xv.w);
        *(ushort4*)((char*)&s_x[0][0] + t * 208 + c4 * 2) = pv;
    }
    for (int i = tid; i < WT * WT; i += 512) s_bias[i / WT][i % WT] = rel_bias[i];
    __syncthreads();

    const char* wq = wsro + WQ_OFF;
    const char* wp = wsro + WP_OFF;
    const float* br = (const float*)(wsro + BR_OFF);
    const float scale = 0.17677669529663687f;  // 1/sqrt(32)

    f32x4 accp[3] = {{0.f,0.f,0.f,0.f},{0.f,0.f,0.f,0.f},{0.f,0.f,0.f,0.f}};

    // x A-fragments (rows 16m..16m+15), reused all heads
    const char* sxrow = (const char*)&s_x[0][0] + (16 * m + ln) * 208 + quad * 16;
    const bf16x8 xa0 = *(const bf16x8*)(sxrow);
    const bf16x8 xa1 = *(const bf16x8*)(sxrow + 64);
    const bf16x8 xa2 = *(const bf16x8*)(sxrow + 128);

    for (int h = 0; h < NH; ++h) {
        // ---- qkv: 3 jobs/wave, nt = hi + 2*jj ----
        #pragma unroll
        for (int jj = 0; jj < 3; ++jj) {
            const int nt = hi + 2 * jj;
            const char* wqp = wq + (size_t)(h * 18 + nt * 3) * 1024 + (size_t)l * 16;
            f32x4 acc = {0.f, 0.f, 0.f, 0.f};
            acc = mfma16(xa0, *(const bf16x8*)(wqp       ), acc);
            acc = mfma16(xa1, *(const bf16x8*)(wqp + 1024), acc);
            acc = mfma16(xa2, *(const bf16x8*)(wqp + 2048), acc);
            const float bias = br[h * CC + nt * 16 + ln];
            if (nt < 4) {  // q (nt 0,1) / k (nt 2,3): row-major [t][e]
                bf16_t* dst = (nt < 2) ? &s_q[0][0] : &s_k[0][0];
                const int col = (nt & 1) * 16 + ln;
                #pragma unroll
                for (int r = 0; r < 4; ++r) {
                    float v = acc[r] + bias;
                    float ov = __shfl_xor(v, 1);
                    if (!(l & 1))
                        *(u32*)((char*)dst + (q0m + r) * 80 + col * 2) = pack2(v, ov);
                }
            } else {       // v: transposed [e][token]
                const int e = (nt - 4) * 16 + ln;
                uint2 pk;
                pk.x = pack2(acc[0] + bias, acc[1] + bias);
                pk.y = pack2(acc[2] + bias, acc[3] + bias);
                *(uint2*)((char*)&s_vT[0][0] + e * 144 + q0m * 2) = pk;
            }
        }
        __syncthreads();  // (1) qkv visible

        // ---- S = QK^T * scale + bias; masked softmax; P (waves 0-3) ----
        if (w < 4) {
            const bf16x8 qa = *(const bf16x8*)((const char*)&s_q[0][0] + (16 * m + ln) * 80 + quad * 16);
            float sv[4][4];
            #pragma unroll
            for (int nt = 0; nt < 4; ++nt) {
                const bf16x8 kb = *(const bf16x8*)((const char*)&s_k[0][0] + (16 * nt + ln) * 80 + quad * 16);
                f32x4 z = {0.f, 0.f, 0.f, 0.f};
                z = mfma16(qa, kb, z);
                const int kk = 16 * nt + ln;
                #pragma unroll
                for (int r = 0; r < 4; ++r) {
                    const int q = q0m + r;
                    float bb = (q < WT && kk < WT) ? s_bias[q][kk] : 0.f;
                    sv[nt][r] = (kk < WT) ? z[r] * scale + bb : -1e30f;
                }
            }
            #pragma unroll
            for (int r = 0; r < 4; ++r) {
                float mx = fmaxf(fmaxf(sv[0][r], sv[1][r]), fmaxf(sv[2][r], sv[3][r]));
                mx = fmaxf(mx, __shfl_xor(mx, 1));
                mx = fmaxf(mx, __shfl_xor(mx, 2));
                mx = fmaxf(mx, __shfl_xor(mx, 4));
                mx = fmaxf(mx, __shfl_xor(mx, 8));
                float s = 0.f;
                #pragma unroll
                for (int nt = 0; nt < 4; ++nt) { sv[nt][r] = __expf(sv[nt][r] - mx); s += sv[nt][r]; }
                s += __shfl_xor(s, 1);
                s += __shfl_xor(s, 2);
                s += __shfl_xor(s, 4);
                s += __shfl_xor(s, 8);
                const float inv = 1.f / s;
                #pragma unroll
                for (int nt = 0; nt < 4; ++nt) sv[nt][r] *= inv;
            }
            #pragma unroll
            for (int nt = 0; nt < 4; ++nt) {
                const int kk = 16 * nt + ln;
                #pragma unroll
                for (int r = 0; r < 4; ++r) {
                    float v = sv[nt][r];
                    float ov = __shfl_xor(v, 1);
                    if (!(l & 1))
                        *(u32*)((char*)&s_p[0][0] + (q0m + r) * 144 + kk * 2) = pack2(v, ov);
                }
            }
        }
        __syncthreads();  // (2) P visible

        // ---- O-tile = P V  (wave job: m-tile m, e-tile hi) ----
        {
            const char* sprow = (const char*)&s_p[0][0] + (16 * m + ln) * 144 + quad * 16;
            const bf16x8 pa0 = *(const bf16x8*)(sprow);
            const bf16x8 pa1 = *(const bf16x8*)(sprow + 64);
            const char* svr = (const char*)&s_vT[0][0] + (16 * hi + ln) * 144 + quad * 16;
            const bf16x8 vb0 = *(const bf16x8*)(svr);
            const bf16x8 vb1 = *(const bf16x8*)(svr + 64);
            f32x4 z = {0.f, 0.f, 0.f, 0.f};
            z = mfma16(pa0, vb0, z);
            z = mfma16(pa1, vb1, z);
            const int col = hi * 16 + ln;  // k-index within this head's 32-slab
            #pragma unroll
            for (int r = 0; r < 4; ++r) {
                float v = z[r];
                float ov = __shfl_xor(v, 1);
                if (!(l & 1))
                    *(u32*)((char*)&s_o[0][0] + (q0m + r) * 80 + col * 2) = pack2(v, ov);
            }
        }
        __syncthreads();  // (3) O visible

        // ---- proj accumulate: A = O rows 16m.. (K=32 slab = head h) ----
        {
            const bf16x8 oa = *(const bf16x8*)((const char*)&s_o[0][0] + (16 * m + ln) * 80 + quad * 16);
            #pragma unroll
            for (int jj = 0; jj < 3; ++jj) {
                const int nt = hi + 2 * jj;
                const char* wpp = wp + (size_t)(nt * 3 + h) * 1024 + (size_t)l * 16;
                accp[jj] = mfma16(oa, *(const bf16x8*)(wpp), accp[jj]);
            }
        }
        // no barrier needed: next-head writers of s_q/s_k/s_vT/s_o are all
        // ordered after next-head syncs (1)/(2); our s_o reads drain at (1).
    }

    // ---- epilogue: out = accp + b_proj, fp32 (B, L, C) ----
    #pragma unroll
    for (int jj = 0; jj < 3; ++jj) {
        const int nt = hi + 2 * jj;
        const int col = nt * 16 + ln;
        const float bp = b_proj[col];
        #pragma unroll
        for (int r = 0; r < 4; ++r) {
            const int t = q0m + r;
            if (t < WT) {
                const int grow = (wy * MM + t / MM) * GH + wx * MM + t % MM;
                out[((size_t)b * LL + grow) * CC + col] = accp[jj][r] + bp;
            }
        }
    }
}

extern "C" void kernel_launch(void* const* d_in, const int* in_sizes, int n_in,
                              void* d_out, int out_size, void* d_ws, size_t ws_size,
                              hipStream_t stream)
{
    const float* x      = (const float*)d_in[0];
    const float* w_qkv  = (const float*)d_in[1];
    const float* b_qkv  = (const float*)d_in[2];
    const float* w_proj = (const float*)d_in[3];
    const float* b_proj = (const float*)d_in[4];
    const float* rb     = (const float*)d_in[5];
    char* ws = (char*)d_ws;

    prep_kernel<<<73, 64, 0, stream>>>(w_qkv, b_qkv, w_proj, ws);
    attn_fused_kernel<<<NB * 64, 512, 0, stream>>>(x, rb, ws, b_proj, (float*)d_out);
}

// Round 4
// 231.874 us; speedup vs baseline: 1.4069x; 1.4069x over previous
//
#include <hip/hip_runtime.h>

typedef unsigned int u32;
typedef __bf16 bf16_t;
typedef bf16_t bf16x8 __attribute__((ext_vector_type(8)));
typedef float f32x4 __attribute__((ext_vector_type(4)));

#define NB 64
#define GH 56
#define CC 96
#define NH 3
#define MM 7
#define WT 49
#define C3 288
#define LL 3136

// ws layout (bytes): weight fragments only
static constexpr size_t WQ_OFF = 0;                  // 54 frags * 1024 B
static constexpr size_t WP_OFF = WQ_OFF + 54 * 1024; // 18 frags * 1024 B
static constexpr size_t BR_OFF = WP_OFF + 18 * 1024; // 288 floats

static __device__ __forceinline__ unsigned short f2bu(float f) {
    union { bf16_t b; unsigned short u; } c; c.b = (bf16_t)f; return c.u;
}
static __device__ __forceinline__ u32 pack2(float a, float b) {
    return (u32)f2bu(a) | ((u32)f2bu(b) << 16);
}
static __device__ __forceinline__ f32x4 mfma16(bf16x8 a, bf16x8 b, f32x4 c) {
    return __builtin_amdgcn_mfma_f32_16x16x32_bf16(a, b, c, 0, 0, 0);
}

// ---------------------------------------------------------------------------
// prep: w_qkv / w_proj -> bf16 B-fragment layout; b_qkv de-interleave.
// B-frag (nt, ks): lane l, elem j = B[32*ks + 8*(l>>4) + j][16*nt + (l&15)]
// qkv col' = which*32 + e  <->  w_qkv col = h*96 + e*3 + which
// ---------------------------------------------------------------------------
__global__ __launch_bounds__(64) void prep_kernel(
    const float* __restrict__ w_qkv, const float* __restrict__ b_qkv,
    const float* __restrict__ w_proj, char* __restrict__ ws)
{
    const int l = threadIdx.x;
    const int blk = blockIdx.x;
    if (blk < 54) {
        const int h = blk / 18, nt = (blk % 18) / 3, ks = blk % 3;
        const int colp = nt * 16 + (l & 15);
        const int e = colp & 31, wh = colp >> 5;
        const int k0 = ks * 32 + (l >> 4) * 8;
        u32 p[4];
        #pragma unroll
        for (int jj = 0; jj < 4; ++jj)
            p[jj] = pack2(w_qkv[(size_t)(k0 + 2*jj    ) * C3 + h * CC + e * 3 + wh],
                          w_qkv[(size_t)(k0 + 2*jj + 1) * C3 + h * CC + e * 3 + wh]);
        uint4 v; v.x = p[0]; v.y = p[1]; v.z = p[2]; v.w = p[3];
        *(uint4*)(ws + WQ_OFF + ((size_t)blk * 64 + l) * 16) = v;
    } else if (blk < 72) {
        const int idx = blk - 54, nt = idx / 3, ks = idx % 3;
        const int n = nt * 16 + (l & 15);
        const int k0 = ks * 32 + (l >> 4) * 8;
        u32 p[4];
        #pragma unroll
        for (int jj = 0; jj < 4; ++jj)
            p[jj] = pack2(w_proj[(size_t)(k0 + 2*jj    ) * CC + n],
                          w_proj[(size_t)(k0 + 2*jj + 1) * CC + n]);
        uint4 v; v.x = p[0]; v.y = p[1]; v.z = p[2]; v.w = p[3];
        *(uint4*)(ws + WP_OFF + ((size_t)idx * 64 + l) * 16) = v;
    } else {
        float* br = (float*)(ws + BR_OFF);
        for (int i = l; i < C3; i += 64) {
            int h = i / CC, c = i % CC;
            br[i] = b_qkv[h * CC + (c & 31) * 3 + (c >> 5)];
        }
    }
}

// ---------------------------------------------------------------------------
// fused: qkv + window attention + proj. One block per (batch, window);
// 4 waves, wave w owns m-tile w in every phase.
// ---------------------------------------------------------------------------
__global__ __launch_bounds__(256, 4) void attn_fused_kernel(
    const float* __restrict__ x, const float* __restrict__ rel_bias,
    const char* __restrict__ wsro, const float* __restrict__ b_proj,
    float* __restrict__ out)
{
    __shared__ bf16_t s_q [64][40];   //  5120 B (Q; reused for O after S-phase)
    __shared__ bf16_t s_k [64][40];   //  5120 B
    __shared__ bf16_t s_vT[32][72];   //  4608 B (V transposed [e][token])
    __shared__ bf16_t s_p [64][72];   //  9216 B
    __shared__ float  s_bias[WT][50]; //  9800 B
    // total 33,864 B -> 4 blocks/CU (16 waves/CU)

    const int tid = threadIdx.x;
    const int l = tid & 63, w = tid >> 6;
    const int ln = l & 15, quad = l >> 4;
    const int b = blockIdx.x >> 6, win = blockIdx.x & 63;
    const int wy = win >> 3, wx = win & 7;
    const int q0m = 16 * w + quad * 4;

    for (int i = tid; i < WT * WT; i += 256) s_bias[i / WT][i % WT] = rel_bias[i];

    // ---- x A-frags straight from global (window is L1-resident) ----
    const int tok = 16 * w + ln;
    const bool tv = tok < WT;
    const int growA = tv ? (wy * MM + tok / MM) * GH + wx * MM + tok % MM : 0;
    const float* xrow = x + ((size_t)b * LL + growA) * CC;
    bf16x8 xa[3];
    #pragma unroll
    for (int ks = 0; ks < 3; ++ks) {
        float4 u = {0.f,0.f,0.f,0.f}, v4 = {0.f,0.f,0.f,0.f};
        if (tv) {
            u  = *(const float4*)(xrow + ks * 32 + quad * 8);
            v4 = *(const float4*)(xrow + ks * 32 + quad * 8 + 4);
        }
        union { u32 p[4]; bf16x8 f; } cv;
        cv.p[0] = pack2(u.x, u.y);  cv.p[1] = pack2(u.z, u.w);
        cv.p[2] = pack2(v4.x, v4.y); cv.p[3] = pack2(v4.z, v4.w);
        xa[ks] = cv.f;
    }
    __syncthreads();  // bias staged

    const char* wq = wsro + WQ_OFF;
    const char* wp = wsro + WP_OFF;
    const float* br = (const float*)(wsro + BR_OFF);
    const float scale = 0.17677669529663687f;  // 1/sqrt(32)

    f32x4 accp[6] = {{0.f,0.f,0.f,0.f},{0.f,0.f,0.f,0.f},{0.f,0.f,0.f,0.f},
                     {0.f,0.f,0.f,0.f},{0.f,0.f,0.f,0.f},{0.f,0.f,0.f,0.f}};

    for (int h = 0; h < NH; ++h) {
        // ---- qkv: all 6 n-tiles per wave ----
        #pragma unroll
        for (int nt = 0; nt < 6; ++nt) {
            const char* wqp = wq + (size_t)(h * 18 + nt * 3) * 1024 + (size_t)l * 16;
            f32x4 acc = {0.f, 0.f, 0.f, 0.f};
            acc = mfma16(xa[0], *(const bf16x8*)(wqp       ), acc);
            acc = mfma16(xa[1], *(const bf16x8*)(wqp + 1024), acc);
            acc = mfma16(xa[2], *(const bf16x8*)(wqp + 2048), acc);
            const float bias = br[h * CC + nt * 16 + ln];
            if (nt < 4) {  // q (nt 0,1) / k (nt 2,3): row-major [token][e]
                bf16_t* dst = (nt < 2) ? &s_q[0][0] : &s_k[0][0];
                const int col = (nt & 1) * 16 + ln;
                #pragma unroll
                for (int r = 0; r < 4; ++r) {
                    float v = acc[r] + bias;
                    float ov = __shfl_xor(v, 1);
                    if (!(l & 1))
                        *(u32*)((char*)dst + (q0m + r) * 80 + col * 2) = pack2(v, ov);
                }
            } else {       // v: transposed [e][token]
                const int e = (nt - 4) * 16 + ln;
                uint2 pk;
                pk.x = pack2(acc[0] + bias, acc[1] + bias);
                pk.y = pack2(acc[2] + bias, acc[3] + bias);
                *(uint2*)((char*)&s_vT[0][0] + e * 144 + q0m * 2) = pk;
            }
        }
        __syncthreads();  // (1) q/k/vT visible

        // ---- S = QK^T*scale + bias; softmax (no max-sub: |logit| small); P ----
        {
            const bf16x8 qa = *(const bf16x8*)((const char*)&s_q[0][0] + (16 * w + ln) * 80 + quad * 16);
            float sv[4][4];
            #pragma unroll
            for (int nt = 0; nt < 4; ++nt) {
                const bf16x8 kb = *(const bf16x8*)((const char*)&s_k[0][0] + (16 * nt + ln) * 80 + quad * 16);
                f32x4 z = {0.f, 0.f, 0.f, 0.f};
                z = mfma16(qa, kb, z);
                const int kk = 16 * nt + ln;
                const int kc = (kk < WT) ? kk : 0;
                #pragma unroll
                for (int r = 0; r < 4; ++r) {
                    const int q = q0m + r;
                    const float bb = s_bias[(q < WT) ? q : 48][kc];
                    sv[nt][r] = (kk < WT) ? __expf(z[r] * scale + bb) : 0.f;
                }
            }
            #pragma unroll
            for (int r = 0; r < 4; ++r) {
                float s = sv[0][r] + sv[1][r] + sv[2][r] + sv[3][r];
                s += __shfl_xor(s, 1);
                s += __shfl_xor(s, 2);
                s += __shfl_xor(s, 4);
                s += __shfl_xor(s, 8);
                const float inv = 1.f / s;
                #pragma unroll
                for (int nt = 0; nt < 4; ++nt) sv[nt][r] *= inv;
            }
            #pragma unroll
            for (int nt = 0; nt < 4; ++nt) {
                const int kk = 16 * nt + ln;
                #pragma unroll
                for (int r = 0; r < 4; ++r) {
                    float v = sv[nt][r];
                    float ov = __shfl_xor(v, 1);
                    if (!(l & 1))
                        *(u32*)((char*)&s_p[0][0] + (q0m + r) * 144 + kk * 2) = pack2(v, ov);
                }
            }
        }
        __syncthreads();  // (2) P visible; Q dead -> s_q reusable for O

        // ---- O = P V (both e-tiles per wave); O -> s_q ----
        {
            const char* sprow = (const char*)&s_p[0][0] + (16 * w + ln) * 144 + quad * 16;
            const bf16x8 pa0 = *(const bf16x8*)(sprow);
            const bf16x8 pa1 = *(const bf16x8*)(sprow + 64);
            #pragma unroll
            for (int nt = 0; nt < 2; ++nt) {
                const char* svr = (const char*)&s_vT[0][0] + (16 * nt + ln) * 144 + quad * 16;
                f32x4 z = {0.f, 0.f, 0.f, 0.f};
                z = mfma16(pa0, *(const bf16x8*)(svr     ), z);
                z = mfma16(pa1, *(const bf16x8*)(svr + 64), z);
                const int col = nt * 16 + ln;
                #pragma unroll
                for (int r = 0; r < 4; ++r) {
                    float v = z[r];
                    float ov = __shfl_xor(v, 1);
                    if (!(l & 1))
                        *(u32*)((char*)&s_q[0][0] + (q0m + r) * 80 + col * 2) = pack2(v, ov);
                }
            }
        }
        __syncthreads();  // (3) O visible

        // ---- proj accumulate: K=32 slab h, all 6 n-tiles per wave ----
        {
            const bf16x8 oa = *(const bf16x8*)((const char*)&s_q[0][0] + (16 * w + ln) * 80 + quad * 16);
            #pragma unroll
            for (int nt = 0; nt < 6; ++nt) {
                const char* wpp = wp + (size_t)(nt * 3 + h) * 1024 + (size_t)l * 16;
                accp[nt] = mfma16(oa, *(const bf16x8*)(wpp), accp[nt]);
            }
        }
        __syncthreads();  // (4) O reads done; s_q free for next head's Q
    }

    // ---- epilogue: full 96-col rows per wave -> full-line writes ----
    #pragma unroll
    for (int r = 0; r < 4; ++r) {
        const int t = q0m + r;
        if (t < WT) {
            const int grow = (wy * MM + t / MM) * GH + wx * MM + t % MM;
            float* orow = out + ((size_t)b * LL + grow) * CC;
            #pragma unroll
            for (int nt = 0; nt < 6; ++nt)
                orow[nt * 16 + ln] = accp[nt][r] + b_proj[nt * 16 + ln];
        }
    }
}

extern "C" void kernel_launch(void* const* d_in, const int* in_sizes, int n_in,
                              void* d_out, int out_size, void* d_ws, size_t ws_size,
                              hipStream_t stream)
{
    const float* x      = (const float*)d_in[0];
    const float* w_qkv  = (const float*)d_in[1];
    const float* b_qkv  = (const float*)d_in[2];
    const float* w_proj = (const float*)d_in[3];
    const float* b_proj = (const float*)d_in[4];
    const float* rb     = (const float*)d_in[5];
    char* ws = (char*)d_ws;

    prep_kernel<<<73, 64, 0, stream>>>(w_qkv, b_qkv, w_proj, ws);
    attn_fused_kernel<<<NB * 64, 256, 0, stream>>>(x, rb, ws, b_proj, (float*)d_out);
}